// Round 4
// baseline (221.801 us; speedup 1.0000x reference)
//
#include <hip/hip_runtime.h>
#include <math.h>

#define C_CH 256
#define T_LEN 4096

// d_ws layout (floats):
//   [c*32 + 0..26]  folded 9-tap weights w[r][k] (r*9+k)
//   [c*32 + 27]     Beff
//   [8192]          (int) completion counter, zeroed by fold_kernel
//   [16384..]       prefetch sink scratch

// ---------------------------------------------------------------------------
// K0: fold conv weights once + zero the tail counter. 1 block, 256 threads.
// ---------------------------------------------------------------------------
template <int K>
__device__ inline void fold_bundle(const float* __restrict__ wp,
                                   const float* __restrict__ bp,
                                   const float* __restrict__ wred6,
                                   int p0, float* __restrict__ w9, float& bacc)
{
    const int off = (9 - K) >> 1;
    #pragma unroll
    for (int k = 0; k < 9; ++k) w9[k] = 0.0f;
    #pragma unroll
    for (int j = 0; j < 6; ++j) {
        const float wr = wred6[j];
        bacc += wr * bp[p0 + j];
        #pragma unroll
        for (int k = 0; k < K; ++k)
            w9[off + k] += wr * wp[(p0 + j) * K + k];
    }
}

__global__ __launch_bounds__(256) void fold_kernel(
    const float* __restrict__ w3, const float* __restrict__ b3,
    const float* __restrict__ w5, const float* __restrict__ b5,
    const float* __restrict__ w9, const float* __restrict__ b9,
    const float* __restrict__ w_red, const float* __restrict__ b_red,
    float* __restrict__ ws)
{
    const int c = threadIdx.x;
    float wf[3][9];
    float bacc = 0.0f;
    #pragma unroll
    for (int r = 0; r < 3; ++r) {
        const int q0 = 18 * c + 6 * r;
        const float* wred6 = w_red + c * 18 + 6 * r;
        if (q0 < 1536)      fold_bundle<3>(w3, b3, wred6, q0,        wf[r], bacc);
        else if (q0 < 3072) fold_bundle<5>(w5, b5, wred6, q0 - 1536, wf[r], bacc);
        else                fold_bundle<9>(w9, b9, wred6, q0 - 3072, wf[r], bacc);
    }
    float* o = ws + c * 32;
    #pragma unroll
    for (int r = 0; r < 3; ++r)
        #pragma unroll
        for (int k = 0; k < 9; ++k) o[r * 9 + k] = wf[r][k];
    o[27] = b_red[c] + bacc;
    o[28] = 0.0f; o[29] = 0.0f; o[30] = 0.0f; o[31] = 0.0f;
    if (c == 0) ((int*)ws)[8192] = 0;   // tail counter
}

// ---------------------------------------------------------------------------
// K1: blocks 0..2047: drive + LIF scan + latency/act, then signal counter.
//     blocks 2048..2055: prefetch MLP weights, spin on counter, run MLP
//     for batch (blk-2048) with warm caches.
// ---------------------------------------------------------------------------
__global__ __launch_bounds__(256) void fused_kernel(
    const float* __restrict__ x, float* __restrict__ ws,
    const float* __restrict__ latency_scale,
    const float* __restrict__ og, const float* __restrict__ bias,
    const float* __restrict__ W1, const float* __restrict__ b1,
    const float* __restrict__ W2, const float* __restrict__ b2,
    float* __restrict__ out_pred, float* __restrict__ out_lat,
    float* __restrict__ out_act, int* __restrict__ counter)
{
    const int blk = blockIdx.x;
    const int tid = threadIdx.x;

    __shared__ float sAct[256];
    __shared__ float sMix[256];
    __shared__ float sH[128];
    __shared__ float sWaveTot[4];
    __shared__ float sCarry[4];
    __shared__ int   sMin[4];

    if (blk >= 2048) {
        // =================== MLP tail block (one per batch) ================
        const int b = blk - 2048;
        const int j = tid;

        // --- prefetch weights while the drive phase runs (warm L1/L2) ---
        float acc = 0.0f;
        {
            const float4* p0 = (const float4*)og;   // 65536 f -> 16384 f4
            for (int i = tid; i < 16384; i += 256) {
                float4 v = p0[i]; acc += v.x + v.y + v.z + v.w;
            }
            const float4* p1 = (const float4*)W1;   // 32768 f -> 8192 f4
            for (int i = tid; i < 8192; i += 256) {
                float4 v = p1[i]; acc += v.x + v.y + v.z + v.w;
            }
            const float4* p2 = (const float4*)W2;   // 32768 f -> 8192 f4
            for (int i = tid; i < 8192; i += 256) {
                float4 v = p2[i]; acc += v.x + v.y + v.z + v.w;
            }
        }
        ws[16384 + b * 256 + tid] = acc;            // sink: keep prefetch alive

        // --- wait for all 2048 drive blocks ---
        if (tid == 0) {
            while (__hip_atomic_load(counter, __ATOMIC_ACQUIRE,
                                     __HIP_MEMORY_SCOPE_AGENT) < 2048) {
                __builtin_amdgcn_s_sleep(8);
            }
        }
        __syncthreads();

        // act: agent-scope loads (bypass possibly-stale local caches)
        sAct[j] = __hip_atomic_load(&out_act[b * 256 + j], __ATOMIC_RELAXED,
                                    __HIP_MEMORY_SCOPE_AGENT);
        __syncthreads();

        // mixed[j] = bias[j] + sum_i act[i] * og[j,i]
        float mix = bias[j];
        const float* ogr = og + (size_t)j * 256;
        #pragma unroll 8
        for (int i = 0; i < 256; ++i) mix = fmaf(sAct[i], ogr[i], mix);
        sMix[j] = mix;
        __syncthreads();

        // h[j] = relu(b1[j] + sum_i mixed[i] * W1[i,j]);  W1 (256,128) row-major
        if (j < 128) {
            float h = b1[j];
            #pragma unroll 8
            for (int i = 0; i < 256; ++i) h = fmaf(sMix[i], W1[i * 128 + j], h);
            sH[j] = fmaxf(h, 0.0f);
        }
        __syncthreads();

        // raw[j] = b2[j] + sum_k h[k] * W2[k,j];  W2 (128,256) row-major
        float raw = b2[j];
        #pragma unroll 8
        for (int k = 0; k < 128; ++k) raw = fmaf(sH[k], W2[k * 256 + j], raw);

        const float sp = fmaxf(raw, 0.0f) + log1pf(expf(-fabsf(raw)));
        out_pred[b * 256 + j] = fminf(fmaxf(sp, 0.0f), 4096.0f);
        return;
    }

    // ======================= drive + scan block ============================
    const int b    = blk >> 8;
    const int c    = blk & 255;
    const int lane = tid & 63;
    const int wv   = tid >> 6;

    // --- x loads: src channels computed arithmetically, issue immediately ---
    const int base = 16 * tid - 4;               // window [t-4, t+4), t in [16*tid, +16)
    float xa[3][24];
    #pragma unroll
    for (int r = 0; r < 3; ++r) {
        const int q      = 18 * c + 6 * r;
        const int region = (q >= 1536) + (q >= 3072);
        const int srcc   = 3 * c + r - (region << 8);
        const float* xr  = x + ((size_t)b * C_CH + srcc) * T_LEN;
        if (tid > 0 && tid < 255) {
            const float4* p = (const float4*)(xr + base);  // base % 4 == 0 -> aligned
            #pragma unroll
            for (int v = 0; v < 6; ++v) {
                float4 q4 = p[v];
                xa[r][4 * v + 0] = q4.x; xa[r][4 * v + 1] = q4.y;
                xa[r][4 * v + 2] = q4.z; xa[r][4 * v + 3] = q4.w;
            }
        } else {
            #pragma unroll
            for (int e = 0; e < 24; ++e) {
                const int t = base + e;
                xa[r][e] = (t >= 0 && t < T_LEN) ? xr[t] : 0.0f;  // conv zero-pad
            }
        }
    }

    // --- folded weights: block-uniform -> scalar loads ---
    const float* wc = ws + c * 32;
    const float Beff = wc[27];
    float d[16];
    #pragma unroll
    for (int tt = 0; tt < 16; ++tt) d[tt] = Beff;
    #pragma unroll
    for (int r = 0; r < 3; ++r) {
        #pragma unroll
        for (int k = 0; k < 9; ++k) {
            const float wk = wc[r * 9 + k];
            #pragma unroll
            for (int tt = 0; tt < 16; ++tt)
                d[tt] = fmaf(wk, xa[r][tt + k], d[tt]);
        }
    }

    const float A   = (float)0.8187307530779818;          // exp(-1/5), fp32
    const float OMA = (float)(1.0 - 0.8187307530779818);  // matches ref rounding

    // --- chunk-local scan: V after 16 steps from 0 ---
    float S = 0.0f;
    #pragma unroll
    for (int tt = 0; tt < 16; ++tt) S = A * S + OMA * d[tt];

    // --- wave-level weighted inclusive scan (per-chunk decay A^16) ---
    const float Fp[6] = {
        (float)4.0762203978366215e-02,  // A^16  = e^-3.2
        (float)1.6615572731739337e-03,  // A^32
        (float)2.7607725720371943e-06,  // A^64
        (float)7.6218649302532563e-12,  // A^128
        (float)5.8092835977683129e-23,  // A^256
        (float)3.3744728758705166e-45   // A^512 (denormal)
    };
    float cinc = S;
    #pragma unroll
    for (int s = 0; s < 6; ++s) {
        const int o = 1 << s;
        const float y = __shfl_up(cinc, o, 64);
        if (lane >= o) cinc = fmaf(Fp[s], y, cinc);
    }
    if (lane == 63) sWaveTot[wv] = cinc;
    __syncthreads();
    if (tid == 0) {
        // A^1024 underflows fp32 -> cross-wave decay factor is exactly 0
        float g = 0.0f;
        #pragma unroll
        for (int w = 0; w < 4; ++w) { sCarry[w] = g; g = sWaveTot[w]; }
    }
    __syncthreads();
    const float cprev = __shfl_up(cinc, 1, 64);
    const float Vin = (lane ? cprev : 0.0f)
                    + expf(-3.2f * (float)lane) * sCarry[wv];

    // --- replay chunk with true incoming V; first threshold crossing ---
    float V = Vin;
    int firstT = T_LEN;
    #pragma unroll
    for (int tt = 0; tt < 16; ++tt) {
        V = A * V + OMA * d[tt];
        if (V >= 1.0f && firstT == T_LEN) firstT = 16 * tid + tt;
    }

    // --- block min-reduce ---
    #pragma unroll
    for (int o = 32; o > 0; o >>= 1)
        firstT = min(firstT, __shfl_xor(firstT, o, 64));
    if (lane == 0) sMin[wv] = firstT;
    __syncthreads();
    if (tid == 0) {
        const int f = min(min(sMin[0], sMin[1]), min(sMin[2], sMin[3]));
        const float lat   = (float)f;                          // T if never fired
        const float scale = fmaxf(latency_scale[0], 0.001f);
        out_lat[blk] = lat;
        out_act[blk] = expf(-lat / scale);
        __threadfence();                    // release lat/act to device scope
        atomicAdd(counter, 1);
    }
}

// ---------------------------------------------------------------------------
extern "C" void kernel_launch(void* const* d_in, const int* in_sizes, int n_in,
                              void* d_out, int out_size, void* d_ws, size_t ws_size,
                              hipStream_t stream) {
    const float* x    = (const float*)d_in[0];
    const float* w3   = (const float*)d_in[1];
    const float* b3   = (const float*)d_in[2];
    const float* w5   = (const float*)d_in[3];
    const float* b5   = (const float*)d_in[4];
    const float* w9   = (const float*)d_in[5];
    const float* b9   = (const float*)d_in[6];
    const float* wred = (const float*)d_in[7];
    const float* bred = (const float*)d_in[8];
    const float* ls   = (const float*)d_in[9];
    const float* og   = (const float*)d_in[10];
    const float* bias = (const float*)d_in[11];
    const float* W1   = (const float*)d_in[12];
    const float* b1   = (const float*)d_in[13];
    const float* W2   = (const float*)d_in[14];
    const float* b2   = (const float*)d_in[15];

    float* ws       = (float*)d_ws;
    int*   counter  = ((int*)d_ws) + 8192;
    float* out      = (float*)d_out;
    float* out_pred = out;              // (8,256)
    float* out_lat  = out + 2048;       // (8,256)
    float* out_act  = out + 4096;       // (8,256)

    fold_kernel<<<1, 256, 0, stream>>>(w3, b3, w5, b5, w9, b9, wred, bred, ws);
    fused_kernel<<<2056, 256, 0, stream>>>(x, ws, ls, og, bias, W1, b1, W2, b2,
                                           out_pred, out_lat, out_act, counter);
}

// Round 5
// 146.675 us; speedup vs baseline: 1.5122x; 1.5122x over previous
//
#include <hip/hip_runtime.h>
#include <math.h>

#define C_CH 256
#define T_LEN 4096

// d_ws layout (floats): [c*32 + 0..26] folded 9-tap weights w[r][k] (r*9+k),
//                       [c*32 + 27] Beff, rest pad. 32 KB total.
// NOTE: no device-scope fences/atomics anywhere in the hot path — on gfx950
// a per-block agent release fence forces a per-XCD L2 writeback (buffer_wbl2);
// 2048 of them serialized R3/R4 at ~120 µs. Kernel boundaries provide
// visibility for free.

// ---------------------------------------------------------------------------
// K0: fold conv weights once. 1 block, 256 threads (one per channel).
// ---------------------------------------------------------------------------
template <int K>
__device__ inline void fold_bundle(const float* __restrict__ wp,
                                   const float* __restrict__ bp,
                                   const float* __restrict__ wred6,
                                   int p0, float* __restrict__ w9, float& bacc)
{
    const int off = (9 - K) >> 1;
    #pragma unroll
    for (int k = 0; k < 9; ++k) w9[k] = 0.0f;
    #pragma unroll
    for (int j = 0; j < 6; ++j) {
        const float wr = wred6[j];
        bacc += wr * bp[p0 + j];
        #pragma unroll
        for (int k = 0; k < K; ++k)
            w9[off + k] += wr * wp[(p0 + j) * K + k];
    }
}

__global__ __launch_bounds__(256) void fold_kernel(
    const float* __restrict__ w3, const float* __restrict__ b3,
    const float* __restrict__ w5, const float* __restrict__ b5,
    const float* __restrict__ w9, const float* __restrict__ b9,
    const float* __restrict__ w_red, const float* __restrict__ b_red,
    float* __restrict__ ws)
{
    const int c = threadIdx.x;
    float wf[3][9];
    float bacc = 0.0f;
    #pragma unroll
    for (int r = 0; r < 3; ++r) {
        const int q0 = 18 * c + 6 * r;
        const float* wred6 = w_red + c * 18 + 6 * r;
        if (q0 < 1536)      fold_bundle<3>(w3, b3, wred6, q0,        wf[r], bacc);
        else if (q0 < 3072) fold_bundle<5>(w5, b5, wred6, q0 - 1536, wf[r], bacc);
        else                fold_bundle<9>(w9, b9, wred6, q0 - 3072, wf[r], bacc);
    }
    float* o = ws + c * 32;
    #pragma unroll
    for (int r = 0; r < 3; ++r)
        #pragma unroll
        for (int k = 0; k < 9; ++k) o[r * 9 + k] = wf[r][k];
    o[27] = b_red[c] + bacc;
    o[28] = 0.0f; o[29] = 0.0f; o[30] = 0.0f; o[31] = 0.0f;
}

// ---------------------------------------------------------------------------
// K1: folded drive + LIF scan + first-crossing latency + act.
// One block per (b, c); 256 threads x 16 t-steps each. No fences.
// ---------------------------------------------------------------------------
__global__ __launch_bounds__(256) void drive_scan_kernel(
    const float* __restrict__ x, const float* __restrict__ ws,
    const float* __restrict__ latency_scale,
    float* __restrict__ out_lat, float* __restrict__ out_act)
{
    const int blk  = blockIdx.x;       // b*256 + c
    const int b    = blk >> 8;
    const int c    = blk & 255;
    const int tid  = threadIdx.x;
    const int lane = tid & 63;
    const int wv   = tid >> 6;

    __shared__ float sWaveTot[4];
    __shared__ float sCarry[4];
    __shared__ int   sMin[4];

    // --- x loads: src channels computed arithmetically, issue immediately ---
    const int base = 16 * tid - 4;               // window [t-4, t+4), t in [16*tid, +16)
    float xa[3][24];
    #pragma unroll
    for (int r = 0; r < 3; ++r) {
        const int q      = 18 * c + 6 * r;
        const int region = (q >= 1536) + (q >= 3072);
        const int srcc   = 3 * c + r - (region << 8);
        const float* xr  = x + ((size_t)b * C_CH + srcc) * T_LEN;
        if (tid > 0 && tid < 255) {
            const float4* p = (const float4*)(xr + base);  // base % 4 == 0 -> aligned
            #pragma unroll
            for (int v = 0; v < 6; ++v) {
                float4 q4 = p[v];
                xa[r][4 * v + 0] = q4.x; xa[r][4 * v + 1] = q4.y;
                xa[r][4 * v + 2] = q4.z; xa[r][4 * v + 3] = q4.w;
            }
        } else {
            #pragma unroll
            for (int e = 0; e < 24; ++e) {
                const int t = base + e;
                xa[r][e] = (t >= 0 && t < T_LEN) ? xr[t] : 0.0f;  // conv zero-pad
            }
        }
    }

    // --- folded weights: block-uniform address -> scalar loads, no LDS ---
    const float* wc = ws + c * 32;
    const float Beff = wc[27];
    float d[16];
    #pragma unroll
    for (int tt = 0; tt < 16; ++tt) d[tt] = Beff;
    #pragma unroll
    for (int r = 0; r < 3; ++r) {
        #pragma unroll
        for (int k = 0; k < 9; ++k) {
            const float wk = wc[r * 9 + k];
            #pragma unroll
            for (int tt = 0; tt < 16; ++tt)
                d[tt] = fmaf(wk, xa[r][tt + k], d[tt]);
        }
    }

    const float A   = (float)0.8187307530779818;          // exp(-1/5), fp32
    const float OMA = (float)(1.0 - 0.8187307530779818);  // matches ref rounding

    // --- chunk-local scan: V after 16 steps from 0 ---
    float S = 0.0f;
    #pragma unroll
    for (int tt = 0; tt < 16; ++tt) S = A * S + OMA * d[tt];

    // --- wave-level weighted inclusive scan (per-chunk decay A^16) ---
    const float Fp[6] = {
        (float)4.0762203978366215e-02,  // A^16  = e^-3.2
        (float)1.6615572731739337e-03,  // A^32
        (float)2.7607725720371943e-06,  // A^64
        (float)7.6218649302532563e-12,  // A^128
        (float)5.8092835977683129e-23,  // A^256
        (float)3.3744728758705166e-45   // A^512 (denormal)
    };
    float cinc = S;
    #pragma unroll
    for (int s = 0; s < 6; ++s) {
        const int o = 1 << s;
        const float y = __shfl_up(cinc, o, 64);
        if (lane >= o) cinc = fmaf(Fp[s], y, cinc);
    }
    if (lane == 63) sWaveTot[wv] = cinc;
    __syncthreads();
    if (tid == 0) {
        // A^1024 underflows fp32 -> cross-wave decay factor is exactly 0
        float g = 0.0f;
        #pragma unroll
        for (int w = 0; w < 4; ++w) { sCarry[w] = g; g = sWaveTot[w]; }
    }
    __syncthreads();
    const float cprev = __shfl_up(cinc, 1, 64);
    const float Vin = (lane ? cprev : 0.0f)
                    + expf(-3.2f * (float)lane) * sCarry[wv];

    // --- replay chunk with true incoming V; first threshold crossing ---
    float V = Vin;
    int firstT = T_LEN;
    #pragma unroll
    for (int tt = 0; tt < 16; ++tt) {
        V = A * V + OMA * d[tt];
        if (V >= 1.0f && firstT == T_LEN) firstT = 16 * tid + tt;
    }

    // --- block min-reduce ---
    #pragma unroll
    for (int o = 32; o > 0; o >>= 1)
        firstT = min(firstT, __shfl_xor(firstT, o, 64));
    if (lane == 0) sMin[wv] = firstT;
    __syncthreads();
    if (tid == 0) {
        const int f = min(min(sMin[0], sMin[1]), min(sMin[2], sMin[3]));
        const float lat   = (float)f;                          // T if never fired
        const float scale = fmaxf(latency_scale[0], 0.001f);
        out_lat[blk] = lat;
        out_act[blk] = expf(-lat / scale);
    }
}

// ---------------------------------------------------------------------------
// K2: gated mix + 2-layer MLP + softplus/clip. One block per batch row;
// 8 blocks fetch the cold 512 KB of weights in parallel.
// ---------------------------------------------------------------------------
__global__ __launch_bounds__(256) void mlp_kernel(
    const float* __restrict__ act,
    const float* __restrict__ og, const float* __restrict__ bias,
    const float* __restrict__ W1, const float* __restrict__ b1,
    const float* __restrict__ W2, const float* __restrict__ b2,
    float* __restrict__ out_pred)
{
    const int b = blockIdx.x;
    const int j = threadIdx.x;
    __shared__ float sAct[256];
    __shared__ float sMix[256];
    __shared__ float sH[128];

    sAct[j] = act[b * 256 + j];
    __syncthreads();

    // mixed[j] = bias[j] + sum_i act[i] * og[j,i]
    float mix = bias[j];
    const float* ogr = og + (size_t)j * 256;
    #pragma unroll 8
    for (int i = 0; i < 256; ++i) mix = fmaf(sAct[i], ogr[i], mix);
    sMix[j] = mix;
    __syncthreads();

    // h[j] = relu(b1[j] + sum_i mixed[i] * W1[i,j]);  W1 (256,128) row-major
    if (j < 128) {
        float h = b1[j];
        #pragma unroll 8
        for (int i = 0; i < 256; ++i) h = fmaf(sMix[i], W1[i * 128 + j], h);
        sH[j] = fmaxf(h, 0.0f);
    }
    __syncthreads();

    // raw[j] = b2[j] + sum_k h[k] * W2[k,j];  W2 (128,256) row-major
    float raw = b2[j];
    #pragma unroll 8
    for (int k = 0; k < 128; ++k) raw = fmaf(sH[k], W2[k * 256 + j], raw);

    const float sp = fmaxf(raw, 0.0f) + log1pf(expf(-fabsf(raw)));
    out_pred[b * 256 + j] = fminf(fmaxf(sp, 0.0f), 4096.0f);
}

// ---------------------------------------------------------------------------
extern "C" void kernel_launch(void* const* d_in, const int* in_sizes, int n_in,
                              void* d_out, int out_size, void* d_ws, size_t ws_size,
                              hipStream_t stream) {
    const float* x    = (const float*)d_in[0];
    const float* w3   = (const float*)d_in[1];
    const float* b3   = (const float*)d_in[2];
    const float* w5   = (const float*)d_in[3];
    const float* b5   = (const float*)d_in[4];
    const float* w9   = (const float*)d_in[5];
    const float* b9   = (const float*)d_in[6];
    const float* wred = (const float*)d_in[7];
    const float* bred = (const float*)d_in[8];
    const float* ls   = (const float*)d_in[9];
    const float* og   = (const float*)d_in[10];
    const float* bias = (const float*)d_in[11];
    const float* W1   = (const float*)d_in[12];
    const float* b1   = (const float*)d_in[13];
    const float* W2   = (const float*)d_in[14];
    const float* b2   = (const float*)d_in[15];

    float* ws       = (float*)d_ws;     // 32 KB folded-weight table
    float* out      = (float*)d_out;
    float* out_pred = out;              // (8,256)
    float* out_lat  = out + 2048;       // (8,256)
    float* out_act  = out + 4096;       // (8,256)

    fold_kernel<<<1, 256, 0, stream>>>(w3, b3, w5, b5, w9, b9, wred, bred, ws);
    drive_scan_kernel<<<2048, 256, 0, stream>>>(x, ws, ls, out_lat, out_act);
    mlp_kernel<<<8, 256, 0, stream>>>(out_act, og, bias, W1, b1, W2, b2, out_pred);
}

// Round 6
// 139.046 us; speedup vs baseline: 1.5952x; 1.0549x over previous
//
#include <hip/hip_runtime.h>
#include <math.h>

#define C_CH 256
#define T_LEN 4096

// Fully fused 2-kernel pipeline. No device-scope fences/atomics (R3/R4: 2048
// per-block agent-release fences serialized the kernel at ~120 us on gfx950's
// non-coherent per-XCD L2s). Kernel boundary provides visibility for free.
//
// drive_scan: one block per (b,c). Each thread owns exactly 16 t-steps and
// loads exactly its 16 floats per source row (4x float4); the +-4 conv halo
// comes from LDS strips (no redundant global traffic; was 1.5x before).
// The 27-tap weight fold (3 dw-convs + grouped 1x1 reduce folded analytically;
// src row = (3c+r) mod 256) is recomputed per block by 28 threads, fully
// unrolled -> one round of load latency, hidden by co-resident blocks.

__global__ __launch_bounds__(256) void drive_scan_kernel(
    const float* __restrict__ x,
    const float* __restrict__ w3, const float* __restrict__ b3,
    const float* __restrict__ w5, const float* __restrict__ b5,
    const float* __restrict__ w9, const float* __restrict__ b9,
    const float* __restrict__ w_red, const float* __restrict__ b_red,
    const float* __restrict__ latency_scale,
    float* __restrict__ out_lat, float* __restrict__ out_act)
{
    const int blk  = blockIdx.x;       // b*256 + c
    const int b    = blk >> 8;
    const int c    = blk & 255;
    const int tid  = threadIdx.x;
    const int lane = tid & 63;
    const int wv   = tid >> 6;

    __shared__ float sWF[28];          // 27 folded taps + Beff at [27]
    __shared__ float sHalo[3][8][256]; // [r][0..3]=thread's first4, [4..7]=last4
    __shared__ float sWaveTot[4];
    __shared__ float sCarry[4];
    __shared__ int   sMin[4];

    // --- exact-tile x loads: 4x float4 per region, no overlap ---
    const int t0 = tid << 4;                       // this thread's 16 steps
    float xv[3][16];
    #pragma unroll
    for (int r = 0; r < 3; ++r) {
        const int src = (3 * c + r) & 255;         // src row = (3c+r) mod 256
        const float4* p = (const float4*)(x + ((size_t)b * C_CH + src) * T_LEN + t0);
        #pragma unroll
        for (int v = 0; v < 4; ++v) {
            float4 q = p[v];
            xv[r][4 * v + 0] = q.x; xv[r][4 * v + 1] = q.y;
            xv[r][4 * v + 2] = q.z; xv[r][4 * v + 3] = q.w;
        }
        #pragma unroll
        for (int k = 0; k < 4; ++k) {
            sHalo[r][k][tid]     = xv[r][k];       // first 4
            sHalo[r][4 + k][tid] = xv[r][12 + k];  // last 4
        }
    }

    // --- parallel in-block weight fold (threads 0..27) ---
    if (tid < 27) {
        const int r = tid / 9, k = tid - 9 * r;
        const int q0     = 18 * c + 6 * r;
        const int region = (q0 >= 1536) + (q0 >= 3072);
        const int p0     = q0 - region * 1536;
        const int K      = (region == 0) ? 3 : (region == 1 ? 5 : 9);
        const int off    = (9 - K) >> 1;
        const float* wP  = (region == 0) ? w3 : (region == 1 ? w5 : w9);
        const int kk     = k - off;
        float w = 0.0f;
        if (kk >= 0 && kk < K) {
            const float* wr = w_red + c * 18 + 6 * r;
            #pragma unroll
            for (int j = 0; j < 6; ++j)
                w = fmaf(wr[j], wP[(p0 + j) * K + kk], w);
        }
        sWF[tid] = w;
    } else if (tid == 27) {
        float acc = b_red[c];
        #pragma unroll
        for (int r = 0; r < 3; ++r) {
            const int q0     = 18 * c + 6 * r;
            const int region = (q0 >= 1536) + (q0 >= 3072);
            const int p0     = q0 - region * 1536;
            const float* bP  = (region == 0) ? b3 : (region == 1 ? b5 : b9);
            const float* wr  = w_red + c * 18 + 6 * r;
            #pragma unroll
            for (int j = 0; j < 6; ++j) acc = fmaf(wr[j], bP[p0 + j], acc);
        }
        sWF[27] = acc;
    }
    __syncthreads();

    // --- drive: 27 FMA per t-step ---
    const float Beff = sWF[27];
    float d[16];
    #pragma unroll
    for (int tt = 0; tt < 16; ++tt) d[tt] = Beff;
    #pragma unroll
    for (int r = 0; r < 3; ++r) {
        float xa[24];                              // window [t0-4, t0+20)
        #pragma unroll
        for (int e = 0; e < 4; ++e)
            xa[e] = tid ? sHalo[r][4 + e][tid - 1] : 0.0f;        // left halo
        #pragma unroll
        for (int e = 0; e < 16; ++e) xa[4 + e] = xv[r][e];
        #pragma unroll
        for (int e = 0; e < 4; ++e)
            xa[20 + e] = (tid < 255) ? sHalo[r][e][tid + 1] : 0.0f; // right halo
        #pragma unroll
        for (int k = 0; k < 9; ++k) {
            const float wk = sWF[r * 9 + k];
            #pragma unroll
            for (int tt = 0; tt < 16; ++tt)
                d[tt] = fmaf(wk, xa[tt + k], d[tt]);
        }
    }

    const float A   = (float)0.8187307530779818;          // exp(-1/5), fp32
    const float OMA = (float)(1.0 - 0.8187307530779818);  // matches ref rounding

    // --- chunk-local scan: V after 16 steps from 0 ---
    float S = 0.0f;
    #pragma unroll
    for (int tt = 0; tt < 16; ++tt) S = A * S + OMA * d[tt];

    // --- wave-level weighted inclusive scan (per-chunk decay A^16) ---
    const float Fp[6] = {
        (float)4.0762203978366215e-02,  // A^16  = e^-3.2
        (float)1.6615572731739337e-03,  // A^32
        (float)2.7607725720371943e-06,  // A^64
        (float)7.6218649302532563e-12,  // A^128
        (float)5.8092835977683129e-23,  // A^256
        (float)3.3744728758705166e-45   // A^512 (denormal)
    };
    float cinc = S;
    #pragma unroll
    for (int s = 0; s < 6; ++s) {
        const int o = 1 << s;
        const float y = __shfl_up(cinc, o, 64);
        if (lane >= o) cinc = fmaf(Fp[s], y, cinc);
    }
    if (lane == 63) sWaveTot[wv] = cinc;
    __syncthreads();
    if (tid == 0) {
        // A^1024 underflows fp32 -> cross-wave decay factor is exactly 0
        float g = 0.0f;
        #pragma unroll
        for (int w = 0; w < 4; ++w) { sCarry[w] = g; g = sWaveTot[w]; }
    }
    __syncthreads();
    const float cprev = __shfl_up(cinc, 1, 64);
    const float Vin = (lane ? cprev : 0.0f)
                    + expf(-3.2f * (float)lane) * sCarry[wv];

    // --- replay chunk with true incoming V; first threshold crossing ---
    float V = Vin;
    int firstT = T_LEN;
    #pragma unroll
    for (int tt = 0; tt < 16; ++tt) {
        V = A * V + OMA * d[tt];
        if (V >= 1.0f && firstT == T_LEN) firstT = t0 + tt;
    }

    // --- block min-reduce ---
    #pragma unroll
    for (int o = 32; o > 0; o >>= 1)
        firstT = min(firstT, __shfl_xor(firstT, o, 64));
    if (lane == 0) sMin[wv] = firstT;
    __syncthreads();
    if (tid == 0) {
        const int f = min(min(sMin[0], sMin[1]), min(sMin[2], sMin[3]));
        const float lat   = (float)f;                          // T if never fired
        const float scale = fmaxf(latency_scale[0], 0.001f);
        out_lat[blk] = lat;
        out_act[blk] = expf(-lat / scale);
    }
}

// ---------------------------------------------------------------------------
// K2: gated mix + 2-layer MLP + softplus/clip. One block per batch row;
// 8 blocks fetch the cold 512 KB of weights in parallel.
// ---------------------------------------------------------------------------
__global__ __launch_bounds__(256) void mlp_kernel(
    const float* __restrict__ act,
    const float* __restrict__ og, const float* __restrict__ bias,
    const float* __restrict__ W1, const float* __restrict__ b1,
    const float* __restrict__ W2, const float* __restrict__ b2,
    float* __restrict__ out_pred)
{
    const int b = blockIdx.x;
    const int j = threadIdx.x;
    __shared__ float sAct[256];
    __shared__ float sMix[256];
    __shared__ float sH[128];

    sAct[j] = act[b * 256 + j];
    __syncthreads();

    // mixed[j] = bias[j] + sum_i act[i] * og[j,i]
    float mix = bias[j];
    const float* ogr = og + (size_t)j * 256;
    #pragma unroll 8
    for (int i = 0; i < 256; ++i) mix = fmaf(sAct[i], ogr[i], mix);
    sMix[j] = mix;
    __syncthreads();

    // h[j] = relu(b1[j] + sum_i mixed[i] * W1[i,j]);  W1 (256,128) row-major
    if (j < 128) {
        float h = b1[j];
        #pragma unroll 8
        for (int i = 0; i < 256; ++i) h = fmaf(sMix[i], W1[i * 128 + j], h);
        sH[j] = fmaxf(h, 0.0f);
    }
    __syncthreads();

    // raw[j] = b2[j] + sum_k h[k] * W2[k,j];  W2 (128,256) row-major
    float raw = b2[j];
    #pragma unroll 8
    for (int k = 0; k < 128; ++k) raw = fmaf(sH[k], W2[k * 256 + j], raw);

    const float sp = fmaxf(raw, 0.0f) + log1pf(expf(-fabsf(raw)));
    out_pred[b * 256 + j] = fminf(fmaxf(sp, 0.0f), 4096.0f);
}

// ---------------------------------------------------------------------------
extern "C" void kernel_launch(void* const* d_in, const int* in_sizes, int n_in,
                              void* d_out, int out_size, void* d_ws, size_t ws_size,
                              hipStream_t stream) {
    const float* x    = (const float*)d_in[0];
    const float* w3   = (const float*)d_in[1];
    const float* b3   = (const float*)d_in[2];
    const float* w5   = (const float*)d_in[3];
    const float* b5   = (const float*)d_in[4];
    const float* w9   = (const float*)d_in[5];
    const float* b9   = (const float*)d_in[6];
    const float* wred = (const float*)d_in[7];
    const float* bred = (const float*)d_in[8];
    const float* ls   = (const float*)d_in[9];
    const float* og   = (const float*)d_in[10];
    const float* bias = (const float*)d_in[11];
    const float* W1   = (const float*)d_in[12];
    const float* b1   = (const float*)d_in[13];
    const float* W2   = (const float*)d_in[14];
    const float* b2   = (const float*)d_in[15];

    float* out      = (float*)d_out;
    float* out_pred = out;              // (8,256)
    float* out_lat  = out + 2048;       // (8,256)
    float* out_act  = out + 4096;       // (8,256)

    drive_scan_kernel<<<2048, 256, 0, stream>>>(
        x, w3, b3, w5, b5, w9, b9, wred, bred, ls, out_lat, out_act);
    mlp_kernel<<<8, 256, 0, stream>>>(out_act, og, bias, W1, b1, W2, b2, out_pred);
}

// Round 7
// 137.939 us; speedup vs baseline: 1.6080x; 1.0080x over previous
//
#include <hip/hip_runtime.h>
#include <math.h>

#define C_CH 256
#define T_LEN 4096

// Fully fused 2-kernel pipeline. No device-scope fences/atomics (R3/R4: 2048
// per-block agent-release fences serialized the kernel at ~120 us on gfx950's
// non-coherent per-XCD L2s). Kernel boundary provides visibility for free.
//
// drive_scan: one block per (b,c). Each thread owns exactly 16 t-steps and
// loads exactly its 16 floats per source row (4x float4); the +-4 conv halo
// comes from LDS strips (no redundant global traffic). The 27-tap weight fold
// (3 dw-convs + grouped 1x1 reduce folded analytically; src row = (3c+r) mod
// 256) is recomputed per block by 28 threads, fully unrolled.
//
// mlp: og is accessed transposed relative to the thread mapping
// (thread j needs og[j][i] for i=0..255 -> 64-line divergent gathers).
// Fixed via 32x257 LDS transpose tiles: coalesced global reads, stride-1
// conflict-free LDS reads. Summation order per thread unchanged (bit-exact).

__global__ __launch_bounds__(256) void drive_scan_kernel(
    const float* __restrict__ x,
    const float* __restrict__ w3, const float* __restrict__ b3,
    const float* __restrict__ w5, const float* __restrict__ b5,
    const float* __restrict__ w9, const float* __restrict__ b9,
    const float* __restrict__ w_red, const float* __restrict__ b_red,
    const float* __restrict__ latency_scale,
    float* __restrict__ out_lat, float* __restrict__ out_act)
{
    const int blk  = blockIdx.x;       // b*256 + c
    const int b    = blk >> 8;
    const int c    = blk & 255;
    const int tid  = threadIdx.x;
    const int lane = tid & 63;
    const int wv   = tid >> 6;

    __shared__ float sWF[28];          // 27 folded taps + Beff at [27]
    __shared__ float sHalo[3][8][256]; // [r][0..3]=thread's first4, [4..7]=last4
    __shared__ float sWaveTot[4];
    __shared__ float sCarry[4];
    __shared__ int   sMin[4];

    // --- exact-tile x loads: 4x float4 per region, no overlap ---
    const int t0 = tid << 4;                       // this thread's 16 steps
    float xv[3][16];
    #pragma unroll
    for (int r = 0; r < 3; ++r) {
        const int src = (3 * c + r) & 255;         // src row = (3c+r) mod 256
        const float4* p = (const float4*)(x + ((size_t)b * C_CH + src) * T_LEN + t0);
        #pragma unroll
        for (int v = 0; v < 4; ++v) {
            float4 q = p[v];
            xv[r][4 * v + 0] = q.x; xv[r][4 * v + 1] = q.y;
            xv[r][4 * v + 2] = q.z; xv[r][4 * v + 3] = q.w;
        }
        #pragma unroll
        for (int k = 0; k < 4; ++k) {
            sHalo[r][k][tid]     = xv[r][k];       // first 4
            sHalo[r][4 + k][tid] = xv[r][12 + k];  // last 4
        }
    }

    // --- parallel in-block weight fold (threads 0..27) ---
    if (tid < 27) {
        const int r = tid / 9, k = tid - 9 * r;
        const int q0     = 18 * c + 6 * r;
        const int region = (q0 >= 1536) + (q0 >= 3072);
        const int p0     = q0 - region * 1536;
        const int K      = (region == 0) ? 3 : (region == 1 ? 5 : 9);
        const int off    = (9 - K) >> 1;
        const float* wP  = (region == 0) ? w3 : (region == 1 ? w5 : w9);
        const int kk     = k - off;
        float w = 0.0f;
        if (kk >= 0 && kk < K) {
            const float* wr = w_red + c * 18 + 6 * r;
            #pragma unroll
            for (int j = 0; j < 6; ++j)
                w = fmaf(wr[j], wP[(p0 + j) * K + kk], w);
        }
        sWF[tid] = w;
    } else if (tid == 27) {
        float acc = b_red[c];
        #pragma unroll
        for (int r = 0; r < 3; ++r) {
            const int q0     = 18 * c + 6 * r;
            const int region = (q0 >= 1536) + (q0 >= 3072);
            const int p0     = q0 - region * 1536;
            const float* bP  = (region == 0) ? b3 : (region == 1 ? b5 : b9);
            const float* wr  = w_red + c * 18 + 6 * r;
            #pragma unroll
            for (int j = 0; j < 6; ++j) acc = fmaf(wr[j], bP[p0 + j], acc);
        }
        sWF[27] = acc;
    }
    __syncthreads();

    // --- drive: 27 FMA per t-step ---
    const float Beff = sWF[27];
    float d[16];
    #pragma unroll
    for (int tt = 0; tt < 16; ++tt) d[tt] = Beff;
    #pragma unroll
    for (int r = 0; r < 3; ++r) {
        float xa[24];                              // window [t0-4, t0+20)
        #pragma unroll
        for (int e = 0; e < 4; ++e)
            xa[e] = tid ? sHalo[r][4 + e][tid - 1] : 0.0f;        // left halo
        #pragma unroll
        for (int e = 0; e < 16; ++e) xa[4 + e] = xv[r][e];
        #pragma unroll
        for (int e = 0; e < 4; ++e)
            xa[20 + e] = (tid < 255) ? sHalo[r][e][tid + 1] : 0.0f; // right halo
        #pragma unroll
        for (int k = 0; k < 9; ++k) {
            const float wk = sWF[r * 9 + k];
            #pragma unroll
            for (int tt = 0; tt < 16; ++tt)
                d[tt] = fmaf(wk, xa[tt + k], d[tt]);
        }
    }

    const float A   = (float)0.8187307530779818;          // exp(-1/5), fp32
    const float OMA = (float)(1.0 - 0.8187307530779818);  // matches ref rounding

    // --- chunk-local scan: V after 16 steps from 0 ---
    float S = 0.0f;
    #pragma unroll
    for (int tt = 0; tt < 16; ++tt) S = A * S + OMA * d[tt];

    // --- wave-level weighted inclusive scan (per-chunk decay A^16) ---
    const float Fp[6] = {
        (float)4.0762203978366215e-02,  // A^16  = e^-3.2
        (float)1.6615572731739337e-03,  // A^32
        (float)2.7607725720371943e-06,  // A^64
        (float)7.6218649302532563e-12,  // A^128
        (float)5.8092835977683129e-23,  // A^256
        (float)3.3744728758705166e-45   // A^512 (denormal)
    };
    float cinc = S;
    #pragma unroll
    for (int s = 0; s < 6; ++s) {
        const int o = 1 << s;
        const float y = __shfl_up(cinc, o, 64);
        if (lane >= o) cinc = fmaf(Fp[s], y, cinc);
    }
    if (lane == 63) sWaveTot[wv] = cinc;
    __syncthreads();
    if (tid == 0) {
        // A^1024 underflows fp32 -> cross-wave decay factor is exactly 0
        float g = 0.0f;
        #pragma unroll
        for (int w = 0; w < 4; ++w) { sCarry[w] = g; g = sWaveTot[w]; }
    }
    __syncthreads();
    const float cprev = __shfl_up(cinc, 1, 64);
    const float Vin = (lane ? cprev : 0.0f)
                    + expf(-3.2f * (float)lane) * sCarry[wv];

    // --- replay chunk with true incoming V; first threshold crossing ---
    float V = Vin;
    int firstT = T_LEN;
    #pragma unroll
    for (int tt = 0; tt < 16; ++tt) {
        V = A * V + OMA * d[tt];
        if (V >= 1.0f && firstT == T_LEN) firstT = t0 + tt;
    }

    // --- block min-reduce ---
    #pragma unroll
    for (int o = 32; o > 0; o >>= 1)
        firstT = min(firstT, __shfl_xor(firstT, o, 64));
    if (lane == 0) sMin[wv] = firstT;
    __syncthreads();
    if (tid == 0) {
        const int f = min(min(sMin[0], sMin[1]), min(sMin[2], sMin[3]));
        const float lat   = (float)f;                          // T if never fired
        const float scale = fmaxf(latency_scale[0], 0.001f);
        out_lat[blk] = lat;
        out_act[blk] = expf(-lat / scale);
    }
}

// ---------------------------------------------------------------------------
// K2: gated mix + 2-layer MLP + softplus/clip. One block per batch row.
// og staged through padded LDS transpose tiles (coalesced global reads,
// conflict-free LDS reads); W1/W2 are already lane-coalesced in global.
// ---------------------------------------------------------------------------
__global__ __launch_bounds__(256) void mlp_kernel(
    const float* __restrict__ act,
    const float* __restrict__ og, const float* __restrict__ bias,
    const float* __restrict__ W1, const float* __restrict__ b1,
    const float* __restrict__ W2, const float* __restrict__ b2,
    float* __restrict__ out_pred)
{
    const int b = blockIdx.x;
    const int j = threadIdx.x;
    __shared__ float sAct[256];
    __shared__ float sOg[32][257];     // i-tile x j, +1 pad breaks conflicts
    __shared__ float sMix[256];
    __shared__ float sH[128];

    sAct[j] = act[b * 256 + j];

    // mixed[j] = bias[j] + sum_i act[i] * og[j,i], i-tiled through LDS.
    // Tile load: flat f = m*256 + tid -> jj = f>>5, ii = f&31; addr jj*256+i0+ii
    // gives two 128B segments per wave instr (coalesced). Summation order over
    // i is still strictly ascending per thread -> bit-identical to before.
    float mix = bias[j];
    for (int i0 = 0; i0 < 256; i0 += 32) {
        __syncthreads();               // protect previous tile's readers
        #pragma unroll
        for (int m = 0; m < 32; ++m) {
            const int f  = (m << 8) + j;
            const int jj = f >> 5;
            const int ii = f & 31;
            sOg[ii][jj] = og[jj * 256 + i0 + ii];
        }
        __syncthreads();
        #pragma unroll
        for (int ii = 0; ii < 32; ++ii)
            mix = fmaf(sAct[i0 + ii], sOg[ii][j], mix);
    }
    sMix[j] = mix;
    __syncthreads();

    // h[j] = relu(b1[j] + sum_i mixed[i] * W1[i,j]);  W1 (256,128) row-major
    if (j < 128) {
        float h = b1[j];
        #pragma unroll 8
        for (int i = 0; i < 256; ++i) h = fmaf(sMix[i], W1[i * 128 + j], h);
        sH[j] = fmaxf(h, 0.0f);
    }
    __syncthreads();

    // raw[j] = b2[j] + sum_k h[k] * W2[k,j];  W2 (128,256) row-major
    float raw = b2[j];
    #pragma unroll 8
    for (int k = 0; k < 128; ++k) raw = fmaf(sH[k], W2[k * 256 + j], raw);

    const float sp = fmaxf(raw, 0.0f) + log1pf(expf(-fabsf(raw)));
    out_pred[b * 256 + j] = fminf(fmaxf(sp, 0.0f), 4096.0f);
}

// ---------------------------------------------------------------------------
extern "C" void kernel_launch(void* const* d_in, const int* in_sizes, int n_in,
                              void* d_out, int out_size, void* d_ws, size_t ws_size,
                              hipStream_t stream) {
    const float* x    = (const float*)d_in[0];
    const float* w3   = (const float*)d_in[1];
    const float* b3   = (const float*)d_in[2];
    const float* w5   = (const float*)d_in[3];
    const float* b5   = (const float*)d_in[4];
    const float* w9   = (const float*)d_in[5];
    const float* b9   = (const float*)d_in[6];
    const float* wred = (const float*)d_in[7];
    const float* bred = (const float*)d_in[8];
    const float* ls   = (const float*)d_in[9];
    const float* og   = (const float*)d_in[10];
    const float* bias = (const float*)d_in[11];
    const float* W1   = (const float*)d_in[12];
    const float* b1   = (const float*)d_in[13];
    const float* W2   = (const float*)d_in[14];
    const float* b2   = (const float*)d_in[15];

    float* out      = (float*)d_out;
    float* out_pred = out;              // (8,256)
    float* out_lat  = out + 2048;       // (8,256)
    float* out_act  = out + 4096;       // (8,256)

    drive_scan_kernel<<<2048, 256, 0, stream>>>(
        x, w3, b3, w5, b5, w9, b9, wred, bred, ls, out_lat, out_act);
    mlp_kernel<<<8, 256, 0, stream>>>(out_act, og, bias, W1, b1, W2, b2, out_pred);
}

// Round 8
// 137.377 us; speedup vs baseline: 1.6145x; 1.0041x over previous
//
#include <hip/hip_runtime.h>
#include <math.h>

#define C_CH 256
#define T_LEN 4096

// 2-kernel pipeline. No device-scope fences/atomics (R3/R4: per-block agent
// release fences on gfx950's non-coherent per-XCD L2s serialized everything).
//
// R8 fix: R3/R4 counters showed VGPR_Count 40-52 while the drive code held
// ~88 live floats -> ~40 floats/thread spilled to scratch (global!) ~ 170 MB
// of hidden traffic. Fixed by (a) per-r restructure (peak live ~60 regs,
// same bit-exact per-d[tt] FMA order: Beff, then r ascending, k ascending),
// (b) __launch_bounds__(256,2) so the allocator may use up to 256 VGPRs.

__global__ __launch_bounds__(256, 2) void drive_scan_kernel(
    const float* __restrict__ x,
    const float* __restrict__ w3, const float* __restrict__ b3,
    const float* __restrict__ w5, const float* __restrict__ b5,
    const float* __restrict__ w9, const float* __restrict__ b9,
    const float* __restrict__ w_red, const float* __restrict__ b_red,
    const float* __restrict__ latency_scale,
    float* __restrict__ out_lat, float* __restrict__ out_act)
{
    const int blk  = blockIdx.x;       // b*256 + c
    const int b    = blk >> 8;
    const int c    = blk & 255;
    const int tid  = threadIdx.x;
    const int lane = tid & 63;
    const int wv   = tid >> 6;

    __shared__ float sWF[28];          // 27 folded taps + Beff at [27]
    __shared__ float sHalo[3][8][256]; // [r][0..3]=own first4, [4..7]=own last4
    __shared__ float sWaveTot[4];
    __shared__ float sCarry[4];
    __shared__ int   sMin[4];

    // --- parallel in-block weight fold (threads 0..27); covered by r=0 barrier
    if (tid < 27) {
        const int r = tid / 9, k = tid - 9 * r;
        const int q0     = 18 * c + 6 * r;
        const int region = (q0 >= 1536) + (q0 >= 3072);
        const int p0     = q0 - region * 1536;
        const int K      = (region == 0) ? 3 : (region == 1 ? 5 : 9);
        const int off    = (9 - K) >> 1;
        const float* wP  = (region == 0) ? w3 : (region == 1 ? w5 : w9);
        const int kk     = k - off;
        float w = 0.0f;
        if (kk >= 0 && kk < K) {
            const float* wr = w_red + c * 18 + 6 * r;
            #pragma unroll
            for (int j = 0; j < 6; ++j)
                w = fmaf(wr[j], wP[(p0 + j) * K + kk], w);
        }
        sWF[tid] = w;
    } else if (tid == 27) {
        float acc = b_red[c];
        #pragma unroll
        for (int r = 0; r < 3; ++r) {
            const int q0     = 18 * c + 6 * r;
            const int region = (q0 >= 1536) + (q0 >= 3072);
            const int p0     = q0 - region * 1536;
            const float* bP  = (region == 0) ? b3 : (region == 1 ? b5 : b9);
            const float* wr  = w_red + c * 18 + 6 * r;
            #pragma unroll
            for (int j = 0; j < 6; ++j) acc = fmaf(wr[j], bP[p0 + j], acc);
        }
        sWF[27] = acc;
    }

    // --- per-r: load own 16 floats, share halo, 9-tap FMA. Low reg pressure.
    const int t0 = tid << 4;
    float d[16];
    #pragma unroll
    for (int r = 0; r < 3; ++r) {
        const int src = (3 * c + r) & 255;         // src row = (3c+r) mod 256
        const float4* p = (const float4*)(x + ((size_t)b * C_CH + src) * T_LEN + t0);
        float xa[24];                              // window [t0-4, t0+20)
        #pragma unroll
        for (int v = 0; v < 4; ++v) {
            float4 q = p[v];
            xa[4 + 4 * v + 0] = q.x; xa[4 + 4 * v + 1] = q.y;
            xa[4 + 4 * v + 2] = q.z; xa[4 + 4 * v + 3] = q.w;
        }
        #pragma unroll
        for (int k = 0; k < 4; ++k) {
            sHalo[r][k][tid]     = xa[4 + k];      // own first 4
            sHalo[r][4 + k][tid] = xa[16 + k];     // own last 4
        }
        __syncthreads();                           // r=0: also covers sWF
        if (r == 0) {
            const float Beff = sWF[27];
            #pragma unroll
            for (int tt = 0; tt < 16; ++tt) d[tt] = Beff;
        }
        #pragma unroll
        for (int e = 0; e < 4; ++e)
            xa[e] = tid ? sHalo[r][4 + e][tid - 1] : 0.0f;          // left halo
        #pragma unroll
        for (int e = 0; e < 4; ++e)
            xa[20 + e] = (tid < 255) ? sHalo[r][e][tid + 1] : 0.0f; // right halo
        #pragma unroll
        for (int k = 0; k < 9; ++k) {
            const float wk = sWF[r * 9 + k];
            #pragma unroll
            for (int tt = 0; tt < 16; ++tt)
                d[tt] = fmaf(wk, xa[tt + k], d[tt]);
        }
    }

    const float A   = (float)0.8187307530779818;          // exp(-1/5), fp32
    const float OMA = (float)(1.0 - 0.8187307530779818);  // matches ref rounding

    // --- chunk-local scan: V after 16 steps from 0 ---
    float S = 0.0f;
    #pragma unroll
    for (int tt = 0; tt < 16; ++tt) S = A * S + OMA * d[tt];

    // --- wave-level weighted inclusive scan (per-chunk decay A^16) ---
    const float Fp[6] = {
        (float)4.0762203978366215e-02,  // A^16  = e^-3.2
        (float)1.6615572731739337e-03,  // A^32
        (float)2.7607725720371943e-06,  // A^64
        (float)7.6218649302532563e-12,  // A^128
        (float)5.8092835977683129e-23,  // A^256
        (float)3.3744728758705166e-45   // A^512 (denormal)
    };
    float cinc = S;
    #pragma unroll
    for (int s = 0; s < 6; ++s) {
        const int o = 1 << s;
        const float y = __shfl_up(cinc, o, 64);
        if (lane >= o) cinc = fmaf(Fp[s], y, cinc);
    }
    if (lane == 63) sWaveTot[wv] = cinc;
    __syncthreads();
    if (tid == 0) {
        // A^1024 underflows fp32 -> cross-wave decay factor is exactly 0
        float g = 0.0f;
        #pragma unroll
        for (int w = 0; w < 4; ++w) { sCarry[w] = g; g = sWaveTot[w]; }
    }
    __syncthreads();
    const float cprev = __shfl_up(cinc, 1, 64);
    const float Vin = (lane ? cprev : 0.0f)
                    + expf(-3.2f * (float)lane) * sCarry[wv];

    // --- replay chunk with true incoming V; first threshold crossing ---
    float V = Vin;
    int firstT = T_LEN;
    #pragma unroll
    for (int tt = 0; tt < 16; ++tt) {
        V = A * V + OMA * d[tt];
        if (V >= 1.0f && firstT == T_LEN) firstT = t0 + tt;
    }

    // --- block min-reduce ---
    #pragma unroll
    for (int o = 32; o > 0; o >>= 1)
        firstT = min(firstT, __shfl_xor(firstT, o, 64));
    if (lane == 0) sMin[wv] = firstT;
    __syncthreads();
    if (tid == 0) {
        const int f = min(min(sMin[0], sMin[1]), min(sMin[2], sMin[3]));
        const float lat   = (float)f;                          // T if never fired
        const float scale = fmaxf(latency_scale[0], 0.001f);
        out_lat[blk] = lat;
        out_act[blk] = expf(-lat / scale);
    }
}

// ---------------------------------------------------------------------------
// K2: gated mix + 2-layer MLP + softplus/clip. One block per batch row.
// og staged through padded LDS transpose tiles (coalesced global reads).
// ---------------------------------------------------------------------------
__global__ __launch_bounds__(256) void mlp_kernel(
    const float* __restrict__ act,
    const float* __restrict__ og, const float* __restrict__ bias,
    const float* __restrict__ W1, const float* __restrict__ b1,
    const float* __restrict__ W2, const float* __restrict__ b2,
    float* __restrict__ out_pred)
{
    const int b = blockIdx.x;
    const int j = threadIdx.x;
    __shared__ float sAct[256];
    __shared__ float sOg[32][257];     // i-tile x j, +1 pad breaks conflicts
    __shared__ float sMix[256];
    __shared__ float sH[128];

    sAct[j] = act[b * 256 + j];

    // mixed[j] = bias[j] + sum_i act[i] * og[j,i], i-tiled through LDS.
    float mix = bias[j];
    for (int i0 = 0; i0 < 256; i0 += 32) {
        __syncthreads();               // protect previous tile's readers
        #pragma unroll
        for (int m = 0; m < 32; ++m) {
            const int f  = (m << 8) + j;
            const int jj = f >> 5;
            const int ii = f & 31;
            sOg[ii][jj] = og[jj * 256 + i0 + ii];
        }
        __syncthreads();
        #pragma unroll
        for (int ii = 0; ii < 32; ++ii)
            mix = fmaf(sAct[i0 + ii], sOg[ii][j], mix);
    }
    sMix[j] = mix;
    __syncthreads();

    // h[j] = relu(b1[j] + sum_i mixed[i] * W1[i,j]);  W1 (256,128) row-major
    if (j < 128) {
        float h = b1[j];
        #pragma unroll 8
        for (int i = 0; i < 256; ++i) h = fmaf(sMix[i], W1[i * 128 + j], h);
        sH[j] = fmaxf(h, 0.0f);
    }
    __syncthreads();

    // raw[j] = b2[j] + sum_k h[k] * W2[k,j];  W2 (128,256) row-major
    float raw = b2[j];
    #pragma unroll 8
    for (int k = 0; k < 128; ++k) raw = fmaf(sH[k], W2[k * 256 + j], raw);

    const float sp = fmaxf(raw, 0.0f) + log1pf(expf(-fabsf(raw)));
    out_pred[b * 256 + j] = fminf(fmaxf(sp, 0.0f), 4096.0f);
}

// ---------------------------------------------------------------------------
extern "C" void kernel_launch(void* const* d_in, const int* in_sizes, int n_in,
                              void* d_out, int out_size, void* d_ws, size_t ws_size,
                              hipStream_t stream) {
    const float* x    = (const float*)d_in[0];
    const float* w3   = (const float*)d_in[1];
    const float* b3   = (const float*)d_in[2];
    const float* w5   = (const float*)d_in[3];
    const float* b5   = (const float*)d_in[4];
    const float* w9   = (const float*)d_in[5];
    const float* b9   = (const float*)d_in[6];
    const float* wred = (const float*)d_in[7];
    const float* bred = (const float*)d_in[8];
    const float* ls   = (const float*)d_in[9];
    const float* og   = (const float*)d_in[10];
    const float* bias = (const float*)d_in[11];
    const float* W1   = (const float*)d_in[12];
    const float* b1   = (const float*)d_in[13];
    const float* W2   = (const float*)d_in[14];
    const float* b2   = (const float*)d_in[15];

    float* out      = (float*)d_out;
    float* out_pred = out;              // (8,256)
    float* out_lat  = out + 2048;       // (8,256)
    float* out_act  = out + 4096;       // (8,256)

    drive_scan_kernel<<<2048, 256, 0, stream>>>(
        x, w3, b3, w5, b5, w9, b9, wred, bred, ls, out_lat, out_act);
    mlp_kernel<<<8, 256, 0, stream>>>(out_act, og, bias, W1, b1, W2, b2, out_pred);
}